// Round 12
// baseline (182.308 us; speedup 1.0000x reference)
//
#include <hip/hip_runtime.h>
#include <hip/hip_bf16.h>

#define H 256
#define NSC 512
#define MQ 4096
#define BATCH 4

typedef __attribute__((ext_vector_type(8))) short bf16x8;
typedef __attribute__((ext_vector_type(4))) float f32x4;

__device__ __forceinline__ ushort f2bf(float x) {
    union { float f; unsigned u; } c; c.f = x;
    unsigned r = c.u + 0x7FFF + ((c.u >> 16) & 1);   // RNE
    return (ushort)(r >> 16);
}
__device__ __forceinline__ unsigned pk2(float hi, float lo) {
    union { float f; unsigned u; } a, b; a.f = hi; b.f = lo;
    return __builtin_amdgcn_perm(a.u, b.u, 0x07060302u);
}
__device__ __forceinline__ uint4 cvt8f(const float* p) {
    float4 a = *(const float4*)p;
    float4 b = *(const float4*)(p + 4);
    uint4 r;
    r.x = pk2(a.y, a.x); r.y = pk2(a.w, a.z);
    r.z = pk2(b.y, b.x); r.w = pk2(b.w, b.z);
    return r;
}
#define EXP2(x) __builtin_amdgcn_exp2f(x)

// ---- bf16 MFMA GEMM body (kv), tile = 64x256, 512 thr = 8 waves.
__device__ __forceinline__ void gemm_body_kv(
    ushort* As, ushort* Bs, int bx, int by,
    const float* __restrict__ Ain, const float* __restrict__ W,
    const float* __restrict__ bias,
    ushort* __restrict__ outk, ushort* __restrict__ out2, int K)
{
    const int t = threadIdx.x;
    const int w = t >> 6, lane = t & 63, g = lane >> 4, l15 = lane & 15;
    const int rowBase = by * 64;
    const int colBase = bx * 256;
    const int wr = (w >> 2) * 32;
    const int wc = (w & 3) * 64;
    f32x4 acc[2][4];
    #pragma unroll
    for (int mt = 0; mt < 2; mt++)
        #pragma unroll
        for (int nt = 0; nt < 4; nt++) acc[mt][nt] = (f32x4){0.f,0.f,0.f,0.f};

    const int sr = t >> 3, skc = t & 7, sp = skc ^ (sr & 7);
    const size_t arow = (size_t)(rowBase + sr) * K + skc * 8;

    uint4 av = cvt8f(Ain + arow);
    uint4 bv[4];
    #pragma unroll
    for (int i = 0; i < 4; i++) {
        const int u = t + 512*i, br = u >> 3, bkc = u & 7;
        bv[i] = cvt8f(W + (size_t)(colBase + br) * K + bkc*8);
    }

    for (int k0 = 0; k0 < K; k0 += 64) {
        __syncthreads();
        *(uint4*)&As[sr*64 + sp*8] = av;
        #pragma unroll
        for (int i = 0; i < 4; i++) {
            const int u = t + 512*i, br = u >> 3, bkc = u & 7, bp = bkc ^ (br & 7);
            *(uint4*)&Bs[br*64 + bp*8] = bv[i];
        }
        __syncthreads();
        if (k0 + 64 < K) {
            av = cvt8f(Ain + arow + k0 + 64);
            #pragma unroll
            for (int i = 0; i < 4; i++) {
                const int u = t + 512*i, br = u >> 3, bkc = u & 7;
                bv[i] = cvt8f(W + (size_t)(colBase + br) * K + k0 + 64 + bkc*8);
            }
        }
        #pragma unroll
        for (int kk = 0; kk < 2; kk++) {
            const int swz = ((kk*4 + g) ^ (l15 & 7)) * 8;
            bf16x8 af[2], bfr[4];
            #pragma unroll
            for (int mt = 0; mt < 2; mt++)
                af[mt] = *(const bf16x8*)&As[(wr + mt*16 + l15)*64 + swz];
            #pragma unroll
            for (int nt = 0; nt < 4; nt++)
                bfr[nt] = *(const bf16x8*)&Bs[(wc + nt*16 + l15)*64 + swz];
            #pragma unroll
            for (int mt = 0; mt < 2; mt++)
                #pragma unroll
                for (int nt = 0; nt < 4; nt++)
                    acc[mt][nt] = __builtin_amdgcn_mfma_f32_16x16x32_bf16(
                        af[mt], bfr[nt], acc[mt][nt], 0, 0, 0);
        }
    }

    #pragma unroll
    for (int nt = 0; nt < 4; nt++) {
        const int col = colBase + wc + nt*16 + l15;
        const float bb = bias[col];
        #pragma unroll
        for (int mt = 0; mt < 2; mt++) {
            const int row0 = rowBase + wr + mt*16 + g*4;
            if (col < 256) {
                #pragma unroll
                for (int r = 0; r < 4; r++)
                    outk[(size_t)(row0 + r) * 256 + col] = f2bf(acc[mt][nt][r] + bb);
            } else {
                ushort4 pkv = { f2bf(acc[mt][nt][0] + bb), f2bf(acc[mt][nt][1] + bb),
                                f2bf(acc[mt][nt][2] + bb), f2bf(acc[mt][nt][3] + bb) };
                *(ushort4*)&out2[(size_t)((row0 >> 9)*256 + col - 256) * 512 + (row0 & 511)] = pkv;
            }
        }
    }
}

// ---- weight bf16 pre-convert (blocks 0..7, dispatched FIRST so it doesn't
// trail the kv-GEMM wave) + kv projection (blocks 8..71).
// Conversion = cvt8f truncation -> mega's staged bits identical to inline cvt.
// wsb layout: Wq[65536] Wo[65536] W1[32768] W2[32768] ushorts, row-major.
__global__ __launch_bounds__(512, 4) void kv_kernel(
    const float* __restrict__ scene,
    const float* __restrict__ in_w, const float* __restrict__ in_b,
    const float* __restrict__ out_w, const float* __restrict__ ff1_w,
    const float* __restrict__ ff2_w,
    ushort* __restrict__ kb, ushort* __restrict__ vtb,
    ushort* __restrict__ wsb)
{
    __shared__ ushort As[64 * 64];
    __shared__ ushort Bs[256 * 64];
    if (blockIdx.x >= 8) {
        const int bid = blockIdx.x - 8;
        gemm_body_kv(As, Bs, bid >> 5, bid & 31,
                     scene, in_w + 65536, in_b + 256, kb, vtb, 256);
    } else {
        const int j = blockIdx.x;                 // 0..7, 24576 elems each
        #pragma unroll
        for (int i = 0; i < 6; i++) {
            const int e = j * 24576 + i * 4096 + (int)threadIdx.x * 8;
            const float* src; int off;
            if (e < 65536)       { src = in_w;  off = e; }
            else if (e < 131072) { src = out_w; off = e - 65536; }
            else if (e < 163840) { src = ff1_w; off = e - 131072; }
            else                 { src = ff2_w; off = e - 163840; }
            *(uint4*)&wsb[e] = cvt8f(src + off);
        }
    }
}

// ---- MEGA (R11 + single-stage phase C): q-proj + attention + FFN, 64 q
// rows per block. 256 blocks x 1024 thr = 16 waves, 1 blk/CU, LDS 145920 B.
//  - B-operand staging loads pre-converted bf16 weights (no cvt8f perms).
//  - phase C: single BK=128 stage (R8-proven code): Bs [256][128], 2 barriers.
// All MFMA/accumulation orders preserved -> bit-identical output.
__global__ __launch_bounds__(1024, 4) void mega_kernel(
    const float* __restrict__ hidden,
    const ushort* __restrict__ Wqb, const float* __restrict__ bq,
    const ushort* __restrict__ k, const ushort* __restrict__ vt,
    const ushort* __restrict__ Wob, const float* __restrict__ bo,
    const float* __restrict__ ag, const float* __restrict__ ab,
    const ushort* __restrict__ W1b, const float* __restrict__ b1,
    const ushort* __restrict__ W2b, const float* __restrict__ b2,
    const float* __restrict__ fg, const float* __restrict__ fbv,
    float* __restrict__ out, float* __restrict__ attn_score,
    float alpha_q)
{
    __shared__ uint4 SHraw[9120];             // 145920 B
    ushort* SH = (ushort*)SHraw;
    // scratch arena [0, 78336) bytes — phase-aliased:
    ushort* Ks  = SH;                         // pass1 [32 key][264]      0..16896
    ushort* Vs  = SH + 8448;                  // pass1 [256 d][40]    16896..37376
    ushort* Pb  = SH + 18688;                 // pass1 16w x [32][40] 37376..78336
    ushort* As0 = SH;                         // phase0 A [64][64]        0..8192
    ushort* Bs0 = SH + 4096;                  // phase0 B [256][64]    8192..40960
    ushort* Bs  = SH;                         // ffn B [256][64|128]      0..65536
    float*  Ls  = (float*)(SH + 16384);       // A/B phases [64][4]   32768..33792
    float*  Lq  = (float*)(SH + 16896);       //                      33792..34816
    float*  LsC = (float*)(SH + 32768);       // phase C (Bs=64KB)    65536..66560
    float*  LqC = (float*)(SH + 33280);       //                      66560..67584
    // persistent / phase-paired:
    ushort* Qb  = SH + 39168;                 // q [64][256] swz      78336..111104
    ushort* Xb  = SH + 39168;                 // ffn x (aliases dead Qb)
    ushort* Cb  = SH + 55552;                 // ctx [64][256] swz   111104..143872
    ushort* Fb  = SH + 55552;                 // ffn f (aliases dead Cb) [64][128]
    float*  Lg  = (float*)(SH + 71936);       // [8 h][64 q]         143872..145920

    const int t = threadIdx.x;
    const int w = t >> 6, lane = t & 63, g = lane >> 4, l15 = lane & 15;
    const int b = blockIdx.x >> 6;
    const int m0 = (blockIdx.x & 63) * 64;
    const size_t rowG = (size_t)b * MQ + m0;      // 64 query rows
    const size_t kg = (size_t)b * NSC * H;
    const size_t vg = (size_t)b * H * NSC;

    const int wr = (w >> 2) * 16;     // 16-wave tiling: 4 row-grp x 16
    const int wc = (w & 3) * 64;      //                 4 col-grp x 64

    // ======= phase 0: q = bf16((hidden@Wq^T + bq)*alpha_q) =================
    {
        f32x4 acc[4];
        #pragma unroll
        for (int nt = 0; nt < 4; nt++) acc[nt] = (f32x4){0.f,0.f,0.f,0.f};

        const int sr = t >> 3, skc = t & 7, sp = skc ^ (sr & 7);
        uint4 av;
        if (t < 512) av = cvt8f(hidden + (rowG + sr) * 256 + skc*8);
        uint4 bv[2];
        #pragma unroll
        for (int i = 0; i < 2; i++) {
            const int u = t + 1024*i, br = u >> 3, bkc = u & 7;
            bv[i] = *(const uint4*)&Wqb[(size_t)br * 256 + bkc*8];
        }
        for (int k0 = 0; k0 < 256; k0 += 64) {
            __syncthreads();
            if (t < 512) *(uint4*)&As0[sr*64 + sp*8] = av;
            #pragma unroll
            for (int i = 0; i < 2; i++) {
                const int u = t + 1024*i, br = u >> 3, bkc = u & 7, bp = bkc ^ (br & 7);
                *(uint4*)&Bs0[br*64 + bp*8] = bv[i];
            }
            __syncthreads();
            if (k0 < 192) {
                if (t < 512) av = cvt8f(hidden + (rowG + sr) * 256 + k0 + 64 + skc*8);
                #pragma unroll
                for (int i = 0; i < 2; i++) {
                    const int u = t + 1024*i, br = u >> 3, bkc = u & 7;
                    bv[i] = *(const uint4*)&Wqb[(size_t)br * 256 + k0 + 64 + bkc*8];
                }
            }
            #pragma unroll
            for (int kk = 0; kk < 2; kk++) {
                const int swz = ((kk*4 + g) ^ (l15 & 7)) * 8;
                bf16x8 af = *(const bf16x8*)&As0[(wr + l15)*64 + swz];
                #pragma unroll
                for (int nt = 0; nt < 4; nt++) {
                    bf16x8 bfr = *(const bf16x8*)&Bs0[(wc + nt*16 + l15)*64 + swz];
                    acc[nt] = __builtin_amdgcn_mfma_f32_16x16x32_bf16(
                        af, bfr, acc[nt], 0, 0, 0);
                }
            }
        }
        #pragma unroll
        for (int nt = 0; nt < 4; nt++) {
            const int col = wc + nt*16 + l15;
            const float bb = bq[col];
            #pragma unroll
            for (int r = 0; r < 4; r++) {
                const int qr = wr + g*4 + r;
                const float o = (acc[nt][r] + bb) * alpha_q;
                Qb[qr*256 + (((col >> 3) ^ (qr & 7)) << 3) + (col & 7)] = f2bf(o);
            }
        }
    }
    __syncthreads();   // Qb complete; phase-0 scratch dead

    // ======= attn pass 1: denominators + ctx (wave = head hh0, half hf) ====
    const int hh0 = w & 7, hf = w >> 3;
    bf16x8 qf[2];
    #pragma unroll
    for (int qt = 0; qt < 2; qt++) {
        const int qr0 = hf*32 + qt*16 + l15;
        qf[qt] = *(const bf16x8*)&Qb[qr0*256 + (((hh0*4 + g) ^ (qr0 & 7)) << 3)];
    }

    f32x4 cacc[2][2];
    float lacc[2][4];
    #pragma unroll
    for (int qt = 0; qt < 2; qt++) {
        #pragma unroll
        for (int dt = 0; dt < 2; dt++) cacc[qt][dt] = (f32x4){0.f,0.f,0.f,0.f};
        #pragma unroll
        for (int r = 0; r < 4; r++) lacc[qt][r] = 0.f;
    }

    // staging: 1024 thr cover 32 keys x 256 d (16KB K + 16KB V)
    const int skey = t >> 5, spart = t & 31;      // K: [key][d granule]
    const int sd = t >> 2, sp2 = t & 3;           // V: [d][key granule]
    bf16x8 kr = *(const bf16x8*)&k[kg + (size_t)skey*H + spart*8];
    bf16x8 vr = *(const bf16x8*)&vt[vg + (size_t)sd*NSC + sp2*8];

    for (int c = 0; c < 16; c++) {
        const int kbase = c * 32;
        __syncthreads();
        *(bf16x8*)&Ks[skey*264 + spart*8] = kr;
        *(bf16x8*)&Vs[sd*40 + sp2*8] = vr;
        __syncthreads();
        if (c < 15) {      // prefetch next chunk; latency hides under compute
            kr = *(const bf16x8*)&k[kg + (size_t)(kbase + 32 + skey)*H + spart*8];
            vr = *(const bf16x8*)&vt[vg + (size_t)sd*NSC + kbase + 32 + sp2*8];
        }
        bf16x8 vfv[2];
        #pragma unroll
        for (int dt = 0; dt < 2; dt++)
            vfv[dt] = *(const bf16x8*)&Vs[(hh0*32 + dt*16 + l15)*40 + g*8];
        #pragma unroll
        for (int qt = 0; qt < 2; qt++) {
            #pragma unroll
            for (int kt = 0; kt < 2; kt++) {
                bf16x8 kf = *(const bf16x8*)&Ks[(kt*16 + l15)*264 + hh0*32 + g*8];
                f32x4 s = __builtin_amdgcn_mfma_f32_16x16x32_bf16(
                    qf[qt], kf, (f32x4){0.f,0.f,0.f,0.f}, 0, 0, 0);
                #pragma unroll
                for (int r = 0; r < 4; r++) {
                    float p = EXP2(s[r]);
                    lacc[qt][r] += p;
                    Pb[(w*32 + qt*16 + g*4 + r)*40 + kt*16 + l15] = f2bf(p);
                }
            }
        }
        #pragma unroll
        for (int qt = 0; qt < 2; qt++) {
            bf16x8 pf = *(const bf16x8*)&Pb[(w*32 + qt*16 + l15)*40 + g*8];
            #pragma unroll
            for (int dt = 0; dt < 2; dt++)
                cacc[qt][dt] = __builtin_amdgcn_mfma_f32_16x16x32_bf16(
                    pf, vfv[dt], cacc[qt][dt], 0, 0, 0);
        }
    }

    // pass-1 epilogue: l-reduce, Lg, ctx -> Cb (swizzled bf16, stays in LDS)
    #pragma unroll
    for (int qt = 0; qt < 2; qt++) {
        float invl[4];
        #pragma unroll
        for (int r = 0; r < 4; r++) {
            float v = lacc[qt][r];
            v += __shfl_xor(v, 1); v += __shfl_xor(v, 2);
            v += __shfl_xor(v, 4); v += __shfl_xor(v, 8);
            invl[r] = 1.f / v;
            if (l15 == 0) Lg[hh0*64 + hf*32 + qt*16 + g*4 + r] = -__log2f(v) - 3.0f;
        }
        #pragma unroll
        for (int dt = 0; dt < 2; dt++)
            #pragma unroll
            for (int r = 0; r < 4; r++) {
                const int qr = hf*32 + qt*16 + g*4 + r;
                const int col = hh0*32 + dt*16 + l15;
                Cb[qr*256 + (((col >> 3) ^ (qr & 7)) << 3) + (col & 7)]
                    = f2bf(cacc[qt][dt][r] * invl[r]);
            }
    }

    __syncthreads();   // pass-1 scratch dead; Cb/Lg complete

    // ======= attn pass 2: attn_score; wave w -> keys [32w, 32w+32) =========
    {
        f32x4 sacc[4][2];
        #pragma unroll
        for (int qt = 0; qt < 4; qt++)
            #pragma unroll
            for (int kt = 0; kt < 2; kt++) sacc[qt][kt] = (f32x4){0.f,0.f,0.f,0.f};

        #pragma unroll 2
        for (int h = 0; h < 8; h++) {
            float lgq[4]; bf16x8 qv[4];
            #pragma unroll
            for (int qt = 0; qt < 4; qt++) {
                lgq[qt] = Lg[h*64 + qt*16 + l15];
                const int qr0 = qt*16 + l15;
                qv[qt] = *(const bf16x8*)&Qb[qr0*256 + (((h*4 + g) ^ (qr0 & 7)) << 3)];
            }
            #pragma unroll
            for (int kt = 0; kt < 2; kt++) {
                bf16x8 kf2 = *(const bf16x8*)&k[kg + (size_t)(w*32 + kt*16 + l15)*H + h*32 + g*8];
                #pragma unroll
                for (int qt = 0; qt < 4; qt++) {
                    f32x4 s = __builtin_amdgcn_mfma_f32_16x16x32_bf16(
                        kf2, qv[qt], (f32x4){0.f,0.f,0.f,0.f}, 0, 0, 0);
                    #pragma unroll
                    for (int r = 0; r < 4; r++) sacc[qt][kt][r] += EXP2(s[r] + lgq[qt]);
                }
            }
        }
        #pragma unroll
        for (int qt = 0; qt < 4; qt++)
            #pragma unroll
            for (int kt = 0; kt < 2; kt++)
                *(f32x4*)&attn_score[(rowG + qt*16 + l15)*NSC + w*32 + kt*16 + g*4]
                    = sacc[qt][kt];
    }

    // ======= ffn phase A: x = LN(ctx @ Wo^T + bo + hid) ====================
    float xres[4][4];
    {
        f32x4 acc[4];
        #pragma unroll
        for (int nt = 0; nt < 4; nt++) acc[nt] = (f32x4){0.f,0.f,0.f,0.f};

        uint4 bv[2];
        #pragma unroll
        for (int i = 0; i < 2; i++) {
            const int u = t + 1024*i, br = u >> 3, bkc = u & 7;
            bv[i] = *(const uint4*)&Wob[(size_t)br * 256 + bkc*8];
        }
        for (int k0 = 0; k0 < 256; k0 += 64) {
            __syncthreads();
            #pragma unroll
            for (int i = 0; i < 2; i++) {
                const int u = t + 1024*i, br = u >> 3, bkc = u & 7, bp = bkc ^ (br & 7);
                *(uint4*)&Bs[br*64 + bp*8] = bv[i];
            }
            __syncthreads();
            if (k0 < 192) {
                #pragma unroll
                for (int i = 0; i < 2; i++) {
                    const int u = t + 1024*i, br = u >> 3, bkc = u & 7;
                    bv[i] = *(const uint4*)&Wob[(size_t)br * 256 + k0 + 64 + bkc*8];
                }
            }
            #pragma unroll
            for (int kk = 0; kk < 2; kk++) {
                const int rowC = wr + l15;
                const int gi = (k0 >> 3) + kk*4 + g;
                bf16x8 af = *(const bf16x8*)&Cb[rowC*256 + ((gi ^ (rowC & 7)) << 3)];
                const int swz = ((kk*4 + g) ^ (l15 & 7)) * 8;
                #pragma unroll
                for (int nt = 0; nt < 4; nt++) {
                    bf16x8 bfr = *(const bf16x8*)&Bs[(wc + nt*16 + l15)*64 + swz];
                    acc[nt] = __builtin_amdgcn_mfma_f32_16x16x32_bf16(
                        af, bfr, acc[nt], 0, 0, 0);
                }
            }
        }
        // epilogue A: + bias + residual, LN, f32 -> xres, bf16 -> Xb
        float bb[4], gmv[4], btv[4];
        #pragma unroll
        for (int nt = 0; nt < 4; nt++) {
            const int col = wc + nt*16 + l15;
            bb[nt] = bo[col]; gmv[nt] = ag[col]; btv[nt] = ab[col];
        }
        #pragma unroll
        for (int r = 0; r < 4; r++) {
            const float* rp = hidden + (rowG + wr + g*4 + r) * 256;
            #pragma unroll
            for (int nt = 0; nt < 4; nt++)
                acc[nt][r] += bb[nt] + rp[wc + nt*16 + l15];
        }
        float ps[4], pq[4];
        #pragma unroll
        for (int r = 0; r < 4; r++) {
            float s = (acc[0][r] + acc[1][r]) + (acc[2][r] + acc[3][r]);
            float qq = (acc[0][r]*acc[0][r] + acc[1][r]*acc[1][r])
                     + (acc[2][r]*acc[2][r] + acc[3][r]*acc[3][r]);
            #pragma unroll
            for (int m = 1; m < 16; m <<= 1) {
                s += __shfl_xor(s, m);
                qq += __shfl_xor(qq, m);
            }
            ps[r] = s; pq[r] = qq;
        }
        if (l15 == 0) {
            #pragma unroll
            for (int r = 0; r < 4; r++) {
                const int ri = wr + g*4 + r;
                Ls[ri*4 + (w & 3)] = ps[r];
                Lq[ri*4 + (w & 3)] = pq[r];
            }
        }
        __syncthreads();
        #pragma unroll
        for (int r = 0; r < 4; r++) {
            const int ri = wr + g*4 + r;
            f32x4 sv = *(const f32x4*)&Ls[ri*4];
            f32x4 qv2 = *(const f32x4*)&Lq[ri*4];
            const float mu = (sv[0]+sv[1]+sv[2]+sv[3]) * (1.f/256.f);
            const float ex2 = (qv2[0]+qv2[1]+qv2[2]+qv2[3]) * (1.f/256.f);
            const float rs = rsqrtf(ex2 - mu*mu + 1e-6f);
            #pragma unroll
            for (int nt = 0; nt < 4; nt++) {
                const int col = wc + nt*16 + l15;
                const float o = (acc[nt][r] - mu) * rs * gmv[nt] + btv[nt];
                xres[nt][r] = o;
                Xb[ri*256 + (((col >> 3) ^ (ri & 7)) << 3) + (col & 7)] = f2bf(o);
            }
        }
    }

    // ======= ffn phase B: f = relu(x @ W1^T + b1) ==========================
    {
        const int wrB = (w >> 2) * 16;
        const int wcB = (w & 3) * 32;
        f32x4 facc[2];
        #pragma unroll
        for (int nt = 0; nt < 2; nt++) facc[nt] = (f32x4){0.f,0.f,0.f,0.f};

        uint4 bv2 = *(const uint4*)&W1b[(size_t)(t >> 3) * 256 + (t & 7)*8];
        for (int k0 = 0; k0 < 256; k0 += 64) {
            __syncthreads();
            {
                const int br = t >> 3, bkc = t & 7, bp = bkc ^ (br & 7);
                *(uint4*)&Bs[br*64 + bp*8] = bv2;
            }
            __syncthreads();
            if (k0 < 192)
                bv2 = *(const uint4*)&W1b[(size_t)(t >> 3) * 256 + k0 + 64 + (t & 7)*8];
            #pragma unroll
            for (int kk = 0; kk < 2; kk++) {
                const int rowX = wrB + l15;
                const int gi = (k0 >> 3) + kk*4 + g;
                bf16x8 af = *(const bf16x8*)&Xb[rowX*256 + ((gi ^ (rowX & 7)) << 3)];
                const int swz = ((kk*4 + g) ^ (l15 & 7)) * 8;
                #pragma unroll
                for (int nt = 0; nt < 2; nt++) {
                    bf16x8 bfr = *(const bf16x8*)&Bs[(wcB + nt*16 + l15)*64 + swz];
                    facc[nt] = __builtin_amdgcn_mfma_f32_16x16x32_bf16(
                        af, bfr, facc[nt], 0, 0, 0);
                }
            }
        }
        __syncthreads();   // phase-A Cb reads done; Fb region quiescent
        #pragma unroll
        for (int nt = 0; nt < 2; nt++) {
            const int colF = wcB + nt*16 + l15;
            const float fbb = b1[colF];
            #pragma unroll
            for (int r = 0; r < 4; r++) {
                const int rowF = wrB + g*4 + r;
                const float o = fmaxf(facc[nt][r] + fbb, 0.f);
                Fb[rowF*128 + (((colF >> 3) ^ (rowF & 7)) << 3) + (colF & 7)] = f2bf(o);
            }
        }
        __syncthreads();
    }

    // ======= ffn phase C: out = LN(f @ W2^T + b2 + x), single K=128 stage ==
    {
        f32x4 acc2[4];
        #pragma unroll
        for (int nt = 0; nt < 4; nt++) acc2[nt] = (f32x4){0.f,0.f,0.f,0.f};

        uint4 bv3[4];
        #pragma unroll
        for (int i = 0; i < 4; i++) {
            const int u = t + 1024*i, br = u >> 4, bgi = u & 15;
            bv3[i] = *(const uint4*)&W2b[(size_t)br * 128 + bgi*8];
        }
        __syncthreads();
        #pragma unroll
        for (int i = 0; i < 4; i++) {
            const int u = t + 1024*i, br = u >> 4, bgi = u & 15;
            *(uint4*)&Bs[br*128 + ((bgi ^ (br & 7)))*8] = bv3[i];
        }
        __syncthreads();
        #pragma unroll
        for (int kk = 0; kk < 4; kk++) {
            const int gi = kk*4 + g;
            const int rowF = wr + l15;
            bf16x8 af2 = *(const bf16x8*)&Fb[rowF*128 + ((gi ^ (rowF & 7)) << 3)];
            const int swz = (gi ^ (l15 & 7)) * 8;
            #pragma unroll
            for (int nt = 0; nt < 4; nt++) {
                bf16x8 bfr = *(const bf16x8*)&Bs[(wc + nt*16 + l15)*128 + swz];
                acc2[nt] = __builtin_amdgcn_mfma_f32_16x16x32_bf16(
                    af2, bfr, acc2[nt], 0, 0, 0);
            }
        }
        float bb[4], gmv[4], btv[4];
        #pragma unroll
        for (int nt = 0; nt < 4; nt++) {
            const int col = wc + nt*16 + l15;
            bb[nt] = b2[col]; gmv[nt] = fg[col]; btv[nt] = fbv[col];
        }
        #pragma unroll
        for (int r = 0; r < 4; r++)
            #pragma unroll
            for (int nt = 0; nt < 4; nt++)
                acc2[nt][r] += bb[nt] + xres[nt][r];
        float ps[4], pq[4];
        #pragma unroll
        for (int r = 0; r < 4; r++) {
            float s = (acc2[0][r] + acc2[1][r]) + (acc2[2][r] + acc2[3][r]);
            float qq = (acc2[0][r]*acc2[0][r] + acc2[1][r]*acc2[1][r])
                     + (acc2[2][r]*acc2[2][r] + acc2[3][r]*acc2[3][r]);
            #pragma unroll
            for (int m = 1; m < 16; m <<= 1) {
                s += __shfl_xor(s, m);
                qq += __shfl_xor(qq, m);
            }
            ps[r] = s; pq[r] = qq;
        }
        __syncthreads();   // Bs dead; LsC region (byte 65536) quiescent
        if (l15 == 0) {
            #pragma unroll
            for (int r = 0; r < 4; r++) {
                const int ri = wr + g*4 + r;
                LsC[ri*4 + (w & 3)] = ps[r];
                LqC[ri*4 + (w & 3)] = pq[r];
            }
        }
        __syncthreads();
        #pragma unroll
        for (int r = 0; r < 4; r++) {
            const int ri = wr + g*4 + r;
            f32x4 sv = *(const f32x4*)&LsC[ri*4];
            f32x4 qv2 = *(const f32x4*)&LqC[ri*4];
            const float mu = (sv[0]+sv[1]+sv[2]+sv[3]) * (1.f/256.f);
            const float ex2 = (qv2[0]+qv2[1]+qv2[2]+qv2[3]) * (1.f/256.f);
            const float rs = rsqrtf(ex2 - mu*mu + 1e-6f);
            #pragma unroll
            for (int nt = 0; nt < 4; nt++) {
                const int col = wc + nt*16 + l15;
                out[(rowG + ri) * 256 + col] =
                    (acc2[nt][r] - mu) * rs * gmv[nt] + btv[nt];
            }
        }
    }
}

extern "C" void kernel_launch(void* const* d_in, const int* in_sizes, int n_in,
                              void* d_out, int out_size, void* d_ws, size_t ws_size,
                              hipStream_t stream)
{
    const float* hidden = (const float*)d_in[0];
    const float* scene  = (const float*)d_in[1];
    const float* in_w   = (const float*)d_in[2];
    const float* in_b   = (const float*)d_in[3];
    const float* out_w  = (const float*)d_in[4];
    const float* out_b  = (const float*)d_in[5];
    const float* aln_g  = (const float*)d_in[6];
    const float* aln_b  = (const float*)d_in[7];
    const float* ff1_w  = (const float*)d_in[8];
    const float* ff1_b  = (const float*)d_in[9];
    const float* ff2_w  = (const float*)d_in[10];
    const float* ff2_b  = (const float*)d_in[11];
    const float* fln_g  = (const float*)d_in[12];
    const float* fln_b  = (const float*)d_in[13];

    float* out0  = (float*)d_out;
    float* score = out0 + (size_t)BATCH * MQ * H;

    ushort* kb   = (ushort*)d_ws;                    // 2048x256 bf16
    ushort* vtb  = kb + 524288;                      // [b][256][512] bf16
    ushort* wsb  = vtb + 524288;                     // bf16 weights: Wq Wo W1 W2

    // (1/sqrt(32)) * log2(e): q pre-scaled so attn uses exp2 directly
    const float alpha_q = 0.25507609683638066f;

    // weight pre-convert (blocks 0..7) + k/vT projection (blocks 8..71)
    kv_kernel<<<dim3(72), dim3(512), 0, stream>>>(
        scene, in_w, in_b, out_w, ff1_w, ff2_w, kb, vtb, wsb);
    // fused q-proj + attention + FFN (bf16 weight staging, 1-stage phase C)
    mega_kernel<<<dim3(256), dim3(1024), 0, stream>>>(
        hidden, wsb, in_b, kb, vtb,
        wsb + 65536, out_b, aln_g, aln_b,
        wsb + 131072, ff1_b, wsb + 163840, ff2_b, fln_g, fln_b,
        out0, score, alpha_q);
}

// Round 13
// 169.619 us; speedup vs baseline: 1.0748x; 1.0748x over previous
//
#include <hip/hip_runtime.h>
#include <hip/hip_bf16.h>

#define H 256
#define NSC 512
#define MQ 4096
#define BATCH 4

typedef __attribute__((ext_vector_type(8))) short bf16x8;
typedef __attribute__((ext_vector_type(4))) float f32x4;

__device__ __forceinline__ ushort f2bf(float x) {
    union { float f; unsigned u; } c; c.f = x;
    unsigned r = c.u + 0x7FFF + ((c.u >> 16) & 1);   // RNE
    return (ushort)(r >> 16);
}
__device__ __forceinline__ unsigned pk2(float hi, float lo) {
    union { float f; unsigned u; } a, b; a.f = hi; b.f = lo;
    return __builtin_amdgcn_perm(a.u, b.u, 0x07060302u);
}
__device__ __forceinline__ uint4 cvt8f(const float* p) {
    float4 a = *(const float4*)p;
    float4 b = *(const float4*)(p + 4);
    uint4 r;
    r.x = pk2(a.y, a.x); r.y = pk2(a.w, a.z);
    r.z = pk2(b.y, b.x); r.w = pk2(b.w, b.z);
    return r;
}
#define EXP2(x) __builtin_amdgcn_exp2f(x)

// ---- bf16 MFMA GEMM body, tile = 64 rows x 256 cols, 512 thr = 8 waves.
// MODE 1: kv split: col<256 -> bf16 k[row*256+col]; col>=256 -> vT
//         out2[((row>>9)*256 + col-256)*512 + (row&511)].
template<int MODE>
__device__ __forceinline__ void gemm_body(
    ushort* As, ushort* Bs, int bx, int by,
    const float* __restrict__ Ain, const float* __restrict__ W,
    const float* __restrict__ bias,
    void* __restrict__ out, ushort* __restrict__ out2,
    int K, int N, float alpha)
{
    const int t = threadIdx.x;
    const int w = t >> 6, lane = t & 63, g = lane >> 4, l15 = lane & 15;
    const int rowBase = by * 64;
    const int colBase = bx * 256;
    const int wr = (w >> 2) * 32;
    const int wc = (w & 3) * 64;
    f32x4 acc[2][4];
    #pragma unroll
    for (int mt = 0; mt < 2; mt++)
        #pragma unroll
        for (int nt = 0; nt < 4; nt++) acc[mt][nt] = (f32x4){0.f,0.f,0.f,0.f};

    const int sr = t >> 3, skc = t & 7, sp = skc ^ (sr & 7);
    const size_t arow = (size_t)(rowBase + sr) * K + skc * 8;

    uint4 av = cvt8f(Ain + arow);
    uint4 bv[4];
    #pragma unroll
    for (int i = 0; i < 4; i++) {
        const int u = t + 512*i, br = u >> 3, bkc = u & 7;
        int brow = colBase + br; if (brow > N - 1) brow = N - 1;
        bv[i] = cvt8f(W + (size_t)brow * K + bkc*8);
    }

    for (int k0 = 0; k0 < K; k0 += 64) {
        __syncthreads();
        *(uint4*)&As[sr*64 + sp*8] = av;
        #pragma unroll
        for (int i = 0; i < 4; i++) {
            const int u = t + 512*i, br = u >> 3, bkc = u & 7, bp = bkc ^ (br & 7);
            *(uint4*)&Bs[br*64 + bp*8] = bv[i];
        }
        __syncthreads();
        if (k0 + 64 < K) {
            av = cvt8f(Ain + arow + k0 + 64);
            #pragma unroll
            for (int i = 0; i < 4; i++) {
                const int u = t + 512*i, br = u >> 3, bkc = u & 7;
                int brow = colBase + br; if (brow > N - 1) brow = N - 1;
                bv[i] = cvt8f(W + (size_t)brow * K + k0 + 64 + bkc*8);
            }
        }
        #pragma unroll
        for (int kk = 0; kk < 2; kk++) {
            const int swz = ((kk*4 + g) ^ (l15 & 7)) * 8;
            bf16x8 af[2], bfr[4];
            #pragma unroll
            for (int mt = 0; mt < 2; mt++)
                af[mt] = *(const bf16x8*)&As[(wr + mt*16 + l15)*64 + swz];
            #pragma unroll
            for (int nt = 0; nt < 4; nt++)
                bfr[nt] = *(const bf16x8*)&Bs[(wc + nt*16 + l15)*64 + swz];
            #pragma unroll
            for (int mt = 0; mt < 2; mt++)
                #pragma unroll
                for (int nt = 0; nt < 4; nt++)
                    acc[mt][nt] = __builtin_amdgcn_mfma_f32_16x16x32_bf16(
                        af[mt], bfr[nt], acc[mt][nt], 0, 0, 0);
        }
    }

    #pragma unroll
    for (int nt = 0; nt < 4; nt++) {
        const int col = colBase + wc + nt*16 + l15;
        const float bb = bias[col];
        #pragma unroll
        for (int mt = 0; mt < 2; mt++) {
            const int row0 = rowBase + wr + mt*16 + g*4;
            if (col < 256) {
                #pragma unroll
                for (int r = 0; r < 4; r++)
                    ((ushort*)out)[(size_t)(row0 + r) * 256 + col] = f2bf(acc[mt][nt][r] + bb);
            } else {
                ushort4 pkv = { f2bf(acc[mt][nt][0] + bb), f2bf(acc[mt][nt][1] + bb),
                                f2bf(acc[mt][nt][2] + bb), f2bf(acc[mt][nt][3] + bb) };
                *(ushort4*)&out2[(size_t)((row0 >> 9)*256 + col - 256) * 512 + (row0 & 511)] = pkv;
            }
        }
    }
}

// ---- kv-only projection: 64 blocks (k bf16 row-major + vT bf16 transposed).
__global__ __launch_bounds__(512, 4) void kv_kernel(
    const float* __restrict__ scene,
    const float* __restrict__ in_w, const float* __restrict__ in_b,
    ushort* __restrict__ kb, ushort* __restrict__ vtb)
{
    __shared__ ushort As[64 * 64];
    __shared__ ushort Bs[256 * 64];
    gemm_body<1>(As, Bs, blockIdx.x >> 5, blockIdx.x & 31,
                 scene, in_w + 65536, in_b + 256, kb, vtb, 256, 512, 1.f);
}

// ---- MEGA: q-projection + attention (64 q rows) + full FFN tail per block.
// 256 blocks x 1024 thr = 16 waves, 1 block/CU, LDS 145.9KB (phase-aliased).
// Phase 0: q = bf16((hidden@Wq^T + bq)*alpha_q) -> Qb in LDS (never leaves CU).
// Pass 1 = R1 attn structure (LDS-staged K/V, register prefetch);
//          16 waves = 8 heads x 2 q-halves, Q read from Qb.
// ctx stays in LDS (Cb) -> ffn phase A reads it directly.
// Pass 2 reads Q from Qb; ffn = 16-wave structure, x residual in VGPRs.
// BEST MEASURED CONFIG (R6: total 167.2us, mega 90.5us) — final.
__global__ __launch_bounds__(1024, 4) void mega_kernel(
    const float* __restrict__ hidden,
    const float* __restrict__ Wq, const float* __restrict__ bq,
    const ushort* __restrict__ k, const ushort* __restrict__ vt,
    const float* __restrict__ Wo, const float* __restrict__ bo,
    const float* __restrict__ ag, const float* __restrict__ ab,
    const float* __restrict__ W1, const float* __restrict__ b1,
    const float* __restrict__ W2, const float* __restrict__ b2,
    const float* __restrict__ fg, const float* __restrict__ fbv,
    float* __restrict__ out, float* __restrict__ attn_score,
    float alpha_q)
{
    __shared__ uint4 SHraw[9120];             // 145920 B
    ushort* SH = (ushort*)SHraw;
    // scratch arena [0, 78336) bytes — phase-aliased:
    ushort* Ks  = SH;                         // pass1 [32 key][264]      0..16896
    ushort* Vs  = SH + 8448;                  // pass1 [256 d][40]    16896..37376
    ushort* Pb  = SH + 18688;                 // pass1 16w x [32][40] 37376..78336
    ushort* As0 = SH;                         // phase0 A [64][64]        0..8192
    ushort* Bs0 = SH + 4096;                  // phase0 B [256][64]    8192..40960
    ushort* Bs  = SH;                         // ffn B [256][64]          0..32768
    float*  Ls  = (float*)(SH + 16384);       // [64][4]              32768..33792
    float*  Lq  = (float*)(SH + 16896);       // [64][4]              33792..34816
    // persistent / phase-paired:
    ushort* Qb  = SH + 39168;                 // q [64][256] swz      78336..111104
    ushort* Xb  = SH + 39168;                 // ffn x (aliases dead Qb)
    ushort* Cb  = SH + 55552;                 // ctx [64][256] swz   111104..143872
    ushort* Fb  = SH + 55552;                 // ffn f (aliases dead Cb) [64][128]
    float*  Lg  = (float*)(SH + 71936);       // [8 h][64 q]         143872..145920

    const int t = threadIdx.x;
    const int w = t >> 6, lane = t & 63, g = lane >> 4, l15 = lane & 15;
    const int b = blockIdx.x >> 6;
    const int m0 = (blockIdx.x & 63) * 64;
    const size_t rowG = (size_t)b * MQ + m0;      // 64 query rows
    const size_t kg = (size_t)b * NSC * H;
    const size_t vg = (size_t)b * H * NSC;

    const int wr = (w >> 2) * 16;     // 16-wave tiling: 4 row-grp x 16
    const int wc = (w & 3) * 64;      //                 4 col-grp x 64

    // ======= phase 0: q = bf16((hidden@Wq^T + bq)*alpha_q) =================
    {
        f32x4 acc[4];
        #pragma unroll
        for (int nt = 0; nt < 4; nt++) acc[nt] = (f32x4){0.f,0.f,0.f,0.f};

        const int sr = t >> 3, skc = t & 7, sp = skc ^ (sr & 7);
        uint4 av;
        if (t < 512) av = cvt8f(hidden + (rowG + sr) * 256 + skc*8);
        uint4 bv[2];
        #pragma unroll
        for (int i = 0; i < 2; i++) {
            const int u = t + 1024*i, br = u >> 3, bkc = u & 7;
            bv[i] = cvt8f(Wq + (size_t)br * 256 + bkc*8);
        }
        for (int k0 = 0; k0 < 256; k0 += 64) {
            __syncthreads();
            if (t < 512) *(uint4*)&As0[sr*64 + sp*8] = av;
            #pragma unroll
            for (int i = 0; i < 2; i++) {
                const int u = t + 1024*i, br = u >> 3, bkc = u & 7, bp = bkc ^ (br & 7);
                *(uint4*)&Bs0[br*64 + bp*8] = bv[i];
            }
            __syncthreads();
            if (k0 < 192) {
                if (t < 512) av = cvt8f(hidden + (rowG + sr) * 256 + k0 + 64 + skc*8);
                #pragma unroll
                for (int i = 0; i < 2; i++) {
                    const int u = t + 1024*i, br = u >> 3, bkc = u & 7;
                    bv[i] = cvt8f(Wq + (size_t)br * 256 + k0 + 64 + bkc*8);
                }
            }
            #pragma unroll
            for (int kk = 0; kk < 2; kk++) {
                const int swz = ((kk*4 + g) ^ (l15 & 7)) * 8;
                bf16x8 af = *(const bf16x8*)&As0[(wr + l15)*64 + swz];
                #pragma unroll
                for (int nt = 0; nt < 4; nt++) {
                    bf16x8 bfr = *(const bf16x8*)&Bs0[(wc + nt*16 + l15)*64 + swz];
                    acc[nt] = __builtin_amdgcn_mfma_f32_16x16x32_bf16(
                        af, bfr, acc[nt], 0, 0, 0);
                }
            }
        }
        #pragma unroll
        for (int nt = 0; nt < 4; nt++) {
            const int col = wc + nt*16 + l15;
            const float bb = bq[col];
            #pragma unroll
            for (int r = 0; r < 4; r++) {
                const int qr = wr + g*4 + r;
                const float o = (acc[nt][r] + bb) * alpha_q;
                Qb[qr*256 + (((col >> 3) ^ (qr & 7)) << 3) + (col & 7)] = f2bf(o);
            }
        }
    }
    __syncthreads();   // Qb complete; phase-0 scratch dead

    // ======= attn pass 1: denominators + ctx (wave = head hh0, half hf) ====
    const int hh0 = w & 7, hf = w >> 3;
    bf16x8 qf[2];
    #pragma unroll
    for (int qt = 0; qt < 2; qt++) {
        const int qr0 = hf*32 + qt*16 + l15;
        const int c0 = hh0*32 + g*8;
        qf[qt] = *(const bf16x8*)&Qb[qr0*256 + (((c0 >> 3) ^ (qr0 & 7)) << 3)];
    }

    f32x4 cacc[2][2];
    float lacc[2][4];
    #pragma unroll
    for (int qt = 0; qt < 2; qt++) {
        #pragma unroll
        for (int dt = 0; dt < 2; dt++) cacc[qt][dt] = (f32x4){0.f,0.f,0.f,0.f};
        #pragma unroll
        for (int r = 0; r < 4; r++) lacc[qt][r] = 0.f;
    }

    // staging assignment: 1024 thr cover 32 keys x 256 d (16KB K + 16KB V)
    const int skey = t >> 5, spart = t & 31;      // K: [key][d granule]
    const int sd = t >> 2, sp2 = t & 3;           // V: [d][key granule]
    bf16x8 kr = *(const bf16x8*)&k[kg + (size_t)skey*H + spart*8];
    bf16x8 vr = *(const bf16x8*)&vt[vg + (size_t)sd*NSC + sp2*8];

    for (int c = 0; c < 16; c++) {
        const int kbase = c * 32;
        __syncthreads();
        *(bf16x8*)&Ks[skey*264 + spart*8] = kr;
        *(bf16x8*)&Vs[sd*40 + sp2*8] = vr;
        __syncthreads();
        if (c < 15) {      // prefetch next chunk; latency hides under compute
            kr = *(const bf16x8*)&k[kg + (size_t)(kbase + 32 + skey)*H + spart*8];
            vr = *(const bf16x8*)&vt[vg + (size_t)sd*NSC + kbase + 32 + sp2*8];
        }
        #pragma unroll
        for (int qt = 0; qt < 2; qt++) {
            #pragma unroll
            for (int kt = 0; kt < 2; kt++) {
                bf16x8 kf = *(const bf16x8*)&Ks[(kt*16 + l15)*264 + hh0*32 + g*8];
                f32x4 s = __builtin_amdgcn_mfma_f32_16x16x32_bf16(
                    qf[qt], kf, (f32x4){0.f,0.f,0.f,0.f}, 0, 0, 0);
                #pragma unroll
                for (int r = 0; r < 4; r++) {
                    float p = EXP2(s[r]);
                    lacc[qt][r] += p;
                    Pb[(w*32 + qt*16 + g*4 + r)*40 + kt*16 + l15] = f2bf(p);
                }
            }
        }
        #pragma unroll
        for (int qt = 0; qt < 2; qt++) {
            bf16x8 pf = *(const bf16x8*)&Pb[(w*32 + qt*16 + l15)*40 + g*8];
            #pragma unroll
            for (int dt = 0; dt < 2; dt++) {
                bf16x8 vf = *(const bf16x8*)&Vs[(hh0*32 + dt*16 + l15)*40 + g*8];
                cacc[qt][dt] = __builtin_amdgcn_mfma_f32_16x16x32_bf16(
                    pf, vf, cacc[qt][dt], 0, 0, 0);
            }
        }
    }

    // pass-1 epilogue: l-reduce, Lg, ctx -> Cb (swizzled bf16, stays in LDS)
    #pragma unroll
    for (int qt = 0; qt < 2; qt++) {
        float invl[4];
        #pragma unroll
        for (int r = 0; r < 4; r++) {
            float v = lacc[qt][r];
            v += __shfl_xor(v, 1); v += __shfl_xor(v, 2);
            v += __shfl_xor(v, 4); v += __shfl_xor(v, 8);
            invl[r] = 1.f / v;
            if (l15 == 0) Lg[hh0*64 + hf*32 + qt*16 + g*4 + r] = -__log2f(v) - 3.0f;
        }
        #pragma unroll
        for (int dt = 0; dt < 2; dt++)
            #pragma unroll
            for (int r = 0; r < 4; r++) {
                const int qr = hf*32 + qt*16 + g*4 + r;
                const int col = hh0*32 + dt*16 + l15;
                Cb[qr*256 + (((col >> 3) ^ (qr & 7)) << 3) + (col & 7)]
                    = f2bf(cacc[qt][dt][r] * invl[r]);
            }
    }

    __syncthreads();   // pass-1 scratch dead; Cb/Lg complete

    // ======= attn pass 2: attn_score; wave w -> keys [32w, 32w+32) =========
    {
        f32x4 sacc[4][2];
        #pragma unroll
        for (int qt = 0; qt < 4; qt++)
            #pragma unroll
            for (int kt = 0; kt < 2; kt++) sacc[qt][kt] = (f32x4){0.f,0.f,0.f,0.f};

        #pragma unroll 2
        for (int h = 0; h < 8; h++) {
            float lgq[4]; bf16x8 qv[4];
            #pragma unroll
            for (int qt = 0; qt < 4; qt++) {
                lgq[qt] = Lg[h*64 + qt*16 + l15];
                const int qr0 = qt*16 + l15;
                const int c0 = h*32 + g*8;
                qv[qt] = *(const bf16x8*)&Qb[qr0*256 + (((c0 >> 3) ^ (qr0 & 7)) << 3)];
            }
            #pragma unroll
            for (int kt = 0; kt < 2; kt++) {
                bf16x8 kf2 = *(const bf16x8*)&k[kg + (size_t)(w*32 + kt*16 + l15)*H + h*32 + g*8];
                #pragma unroll
                for (int qt = 0; qt < 4; qt++) {
                    f32x4 s = __builtin_amdgcn_mfma_f32_16x16x32_bf16(
                        kf2, qv[qt], (f32x4){0.f,0.f,0.f,0.f}, 0, 0, 0);
                    #pragma unroll
                    for (int r = 0; r < 4; r++) sacc[qt][kt][r] += EXP2(s[r] + lgq[qt]);
                }
            }
        }
        #pragma unroll
        for (int qt = 0; qt < 4; qt++)
            #pragma unroll
            for (int kt = 0; kt < 2; kt++)
                *(f32x4*)&attn_score[(rowG + qt*16 + l15)*NSC + w*32 + kt*16 + g*4]
                    = sacc[qt][kt];
    }

    // ======= ffn phase A: x = LN(ctx @ Wo^T + bo + hid) ====================
    float xres[4][4];
    {
        f32x4 acc[4];
        #pragma unroll
        for (int nt = 0; nt < 4; nt++) acc[nt] = (f32x4){0.f,0.f,0.f,0.f};

        uint4 bv[2];
        #pragma unroll
        for (int i = 0; i < 2; i++) {
            const int u = t + 1024*i, br = u >> 3, bkc = u & 7;
            bv[i] = cvt8f(Wo + (size_t)br * 256 + bkc*8);
        }
        for (int k0 = 0; k0 < 256; k0 += 64) {
            __syncthreads();
            #pragma unroll
            for (int i = 0; i < 2; i++) {
                const int u = t + 1024*i, br = u >> 3, bkc = u & 7, bp = bkc ^ (br & 7);
                *(uint4*)&Bs[br*64 + bp*8] = bv[i];
            }
            __syncthreads();
            if (k0 < 192) {
                #pragma unroll
                for (int i = 0; i < 2; i++) {
                    const int u = t + 1024*i, br = u >> 3, bkc = u & 7;
                    bv[i] = cvt8f(Wo + (size_t)br * 256 + k0 + 64 + bkc*8);
                }
            }
            #pragma unroll
            for (int kk = 0; kk < 2; kk++) {
                const int rowC = wr + l15;
                const int gi = (k0 >> 3) + kk*4 + g;
                bf16x8 af = *(const bf16x8*)&Cb[rowC*256 + ((gi ^ (rowC & 7)) << 3)];
                const int swz = ((kk*4 + g) ^ (l15 & 7)) * 8;
                #pragma unroll
                for (int nt = 0; nt < 4; nt++) {
                    bf16x8 bfr = *(const bf16x8*)&Bs[(wc + nt*16 + l15)*64 + swz];
                    acc[nt] = __builtin_amdgcn_mfma_f32_16x16x32_bf16(
                        af, bfr, acc[nt], 0, 0, 0);
                }
            }
        }
        // epilogue A: + bias + residual, LN, f32 -> xres, bf16 -> Xb
        float bb[4], gmv[4], btv[4];
        #pragma unroll
        for (int nt = 0; nt < 4; nt++) {
            const int col = wc + nt*16 + l15;
            bb[nt] = bo[col]; gmv[nt] = ag[col]; btv[nt] = ab[col];
        }
        #pragma unroll
        for (int r = 0; r < 4; r++) {
            const float* rp = hidden + (rowG + wr + g*4 + r) * 256;
            #pragma unroll
            for (int nt = 0; nt < 4; nt++)
                acc[nt][r] += bb[nt] + rp[wc + nt*16 + l15];
        }
        float ps[4], pq[4];
        #pragma unroll
        for (int r = 0; r < 4; r++) {
            float s = (acc[0][r] + acc[1][r]) + (acc[2][r] + acc[3][r]);
            float qq = (acc[0][r]*acc[0][r] + acc[1][r]*acc[1][r])
                     + (acc[2][r]*acc[2][r] + acc[3][r]*acc[3][r]);
            #pragma unroll
            for (int m = 1; m < 16; m <<= 1) {
                s += __shfl_xor(s, m);
                qq += __shfl_xor(qq, m);
            }
            ps[r] = s; pq[r] = qq;
        }
        if (l15 == 0) {
            #pragma unroll
            for (int r = 0; r < 4; r++) {
                const int ri = wr + g*4 + r;
                Ls[ri*4 + (w & 3)] = ps[r];
                Lq[ri*4 + (w & 3)] = pq[r];
            }
        }
        __syncthreads();
        #pragma unroll
        for (int r = 0; r < 4; r++) {
            const int ri = wr + g*4 + r;
            f32x4 sv = *(const f32x4*)&Ls[ri*4];
            f32x4 qv2 = *(const f32x4*)&Lq[ri*4];
            const float mu = (sv[0]+sv[1]+sv[2]+sv[3]) * (1.f/256.f);
            const float ex2 = (qv2[0]+qv2[1]+qv2[2]+qv2[3]) * (1.f/256.f);
            const float rs = rsqrtf(ex2 - mu*mu + 1e-6f);
            #pragma unroll
            for (int nt = 0; nt < 4; nt++) {
                const int col = wc + nt*16 + l15;
                const float o = (acc[nt][r] - mu) * rs * gmv[nt] + btv[nt];
                xres[nt][r] = o;
                Xb[ri*256 + (((col >> 3) ^ (ri & 7)) << 3) + (col & 7)] = f2bf(o);
            }
        }
    }

    // ======= ffn phase B: f = relu(x @ W1^T + b1) ==========================
    {
        const int wrB = (w >> 2) * 16;
        const int wcB = (w & 3) * 32;
        f32x4 facc[2];
        #pragma unroll
        for (int nt = 0; nt < 2; nt++) facc[nt] = (f32x4){0.f,0.f,0.f,0.f};

        uint4 bv2 = cvt8f(W1 + (size_t)(t >> 3) * 256 + (t & 7)*8);
        for (int k0 = 0; k0 < 256; k0 += 64) {
            __syncthreads();
            {
                const int br = t >> 3, bkc = t & 7, bp = bkc ^ (br & 7);
                *(uint4*)&Bs[br*64 + bp*8] = bv2;
            }
            __syncthreads();
            if (k0 < 192)
                bv2 = cvt8f(W1 + (size_t)(t >> 3) * 256 + k0 + 64 + (t & 7)*8);
            #pragma unroll
            for (int kk = 0; kk < 2; kk++) {
                const int rowX = wrB + l15;
                const int gi = (k0 >> 3) + kk*4 + g;
                bf16x8 af = *(const bf16x8*)&Xb[rowX*256 + ((gi ^ (rowX & 7)) << 3)];
                const int swz = ((kk*4 + g) ^ (l15 & 7)) * 8;
                #pragma unroll
                for (int nt = 0; nt < 2; nt++) {
                    bf16x8 bfr = *(const bf16x8*)&Bs[(wcB + nt*16 + l15)*64 + swz];
                    facc[nt] = __builtin_amdgcn_mfma_f32_16x16x32_bf16(
                        af, bfr, facc[nt], 0, 0, 0);
                }
            }
        }
        __syncthreads();   // Fb aliases dead Cb: phase-A Cb reads done
        #pragma unroll
        for (int nt = 0; nt < 2; nt++) {
            const int colF = wcB + nt*16 + l15;
            const float fbb = b1[colF];
            #pragma unroll
            for (int r = 0; r < 4; r++) {
                const int rowF = wrB + g*4 + r;
                const float o = fmaxf(facc[nt][r] + fbb, 0.f);
                Fb[rowF*128 + (((colF >> 3) ^ (rowF & 7)) << 3) + (colF & 7)] = f2bf(o);
            }
        }
        __syncthreads();
    }

    // ======= ffn phase C: out = LN(f @ W2^T + b2 + x) ======================
    {
        f32x4 acc2[4];
        #pragma unroll
        for (int nt = 0; nt < 4; nt++) acc2[nt] = (f32x4){0.f,0.f,0.f,0.f};

        uint4 bv3[2];
        #pragma unroll
        for (int i = 0; i < 2; i++) {
            const int u = t + 1024*i, br = u >> 3, bkc = u & 7;
            bv3[i] = cvt8f(W2 + (size_t)br * 128 + bkc*8);
        }
        for (int k0 = 0; k0 < 128; k0 += 64) {
            __syncthreads();
            #pragma unroll
            for (int i = 0; i < 2; i++) {
                const int u = t + 1024*i, br = u >> 3, bkc = u & 7, bp = bkc ^ (br & 7);
                *(uint4*)&Bs[br*64 + bp*8] = bv3[i];
            }
            __syncthreads();
            if (k0 == 0) {
                #pragma unroll
                for (int i = 0; i < 2; i++) {
                    const int u = t + 1024*i, br = u >> 3, bkc = u & 7;
                    bv3[i] = cvt8f(W2 + (size_t)br * 128 + 64 + bkc*8);
                }
            }
            #pragma unroll
            for (int kk = 0; kk < 2; kk++) {
                const int gi = (k0 >> 3) + kk*4 + g;
                const int rowF = wr + l15;
                bf16x8 af2 = *(const bf16x8*)&Fb[rowF*128 + ((gi ^ (rowF & 7)) << 3)];
                const int swz = ((kk*4 + g) ^ (l15 & 7)) * 8;
                #pragma unroll
                for (int nt = 0; nt < 4; nt++) {
                    bf16x8 bfr = *(const bf16x8*)&Bs[(wc + nt*16 + l15)*64 + swz];
                    acc2[nt] = __builtin_amdgcn_mfma_f32_16x16x32_bf16(
                        af2, bfr, acc2[nt], 0, 0, 0);
                }
            }
        }
        float bb[4], gmv[4], btv[4];
        #pragma unroll
        for (int nt = 0; nt < 4; nt++) {
            const int col = wc + nt*16 + l15;
            bb[nt] = b2[col]; gmv[nt] = fg[col]; btv[nt] = fbv[col];
        }
        #pragma unroll
        for (int r = 0; r < 4; r++)
            #pragma unroll
            for (int nt = 0; nt < 4; nt++)
                acc2[nt][r] += bb[nt] + xres[nt][r];
        float ps[4], pq[4];
        #pragma unroll
        for (int r = 0; r < 4; r++) {
            float s = (acc2[0][r] + acc2[1][r]) + (acc2[2][r] + acc2[3][r]);
            float qq = (acc2[0][r]*acc2[0][r] + acc2[1][r]*acc2[1][r])
                     + (acc2[2][r]*acc2[2][r] + acc2[3][r]*acc2[3][r]);
            #pragma unroll
            for (int m = 1; m < 16; m <<= 1) {
                s += __shfl_xor(s, m);
                qq += __shfl_xor(qq, m);
            }
            ps[r] = s; pq[r] = qq;
        }
        __syncthreads();   // Ls/Lq reuse guard
        if (l15 == 0) {
            #pragma unroll
            for (int r = 0; r < 4; r++) {
                const int ri = wr + g*4 + r;
                Ls[ri*4 + (w & 3)] = ps[r];
                Lq[ri*4 + (w & 3)] = pq[r];
            }
        }
        __syncthreads();
        #pragma unroll
        for (int r = 0; r < 4; r++) {
            const int ri = wr + g*4 + r;
            f32x4 sv = *(const f32x4*)&Ls[ri*4];
            f32x4 qv2 = *(const f32x4*)&Lq[ri*4];
            const float mu = (sv[0]+sv[1]+sv[2]+sv[3]) * (1.f/256.f);
            const float ex2 = (qv2[0]+qv2[1]+qv2[2]+qv2[3]) * (1.f/256.f);
            const float rs = rsqrtf(ex2 - mu*mu + 1e-6f);
            #pragma unroll
            for (int nt = 0; nt < 4; nt++) {
                const int col = wc + nt*16 + l15;
                out[(rowG + ri) * 256 + col] =
                    (acc2[nt][r] - mu) * rs * gmv[nt] + btv[nt];
            }
        }
    }
}

extern "C" void kernel_launch(void* const* d_in, const int* in_sizes, int n_in,
                              void* d_out, int out_size, void* d_ws, size_t ws_size,
                              hipStream_t stream)
{
    const float* hidden = (const float*)d_in[0];
    const float* scene  = (const float*)d_in[1];
    const float* in_w   = (const float*)d_in[2];
    const float* in_b   = (const float*)d_in[3];
    const float* out_w  = (const float*)d_in[4];
    const float* out_b  = (const float*)d_in[5];
    const float* aln_g  = (const float*)d_in[6];
    const float* aln_b  = (const float*)d_in[7];
    const float* ff1_w  = (const float*)d_in[8];
    const float* ff1_b  = (const float*)d_in[9];
    const float* ff2_w  = (const float*)d_in[10];
    const float* ff2_b  = (const float*)d_in[11];
    const float* fln_g  = (const float*)d_in[12];
    const float* fln_b  = (const float*)d_in[13];

    float* out0  = (float*)d_out;
    float* score = out0 + (size_t)BATCH * MQ * H;

    ushort* kb   = (ushort*)d_ws;                    // 2048x256 bf16
    ushort* vtb  = kb + 524288;                      // [b][256][512] bf16

    // (1/sqrt(32)) * log2(e): q pre-scaled so attn uses exp2 directly
    const float alpha_q = 0.25507609683638066f;

    // k/vT projection (64 blocks)
    kv_kernel<<<dim3(64), dim3(512), 0, stream>>>(scene, in_w, in_b, kb, vtb);
    // fused q-proj + attention + FFN: q and ctx never leave LDS
    mega_kernel<<<dim3(256), dim3(1024), 0, stream>>>(
        hidden, in_w, in_b, kb, vtb,
        out_w, out_b, aln_g, aln_b,
        ff1_w, ff1_b, ff2_w, ff2_b, fln_g, fln_b,
        out0, score, alpha_q);
}

// Round 14
// 166.211 us; speedup vs baseline: 1.0968x; 1.0205x over previous
//
#include <hip/hip_runtime.h>
#include <hip/hip_bf16.h>

#define H 256
#define NSC 512
#define MQ 4096
#define BATCH 4

typedef __attribute__((ext_vector_type(8))) short bf16x8;
typedef __attribute__((ext_vector_type(4))) float f32x4;

__device__ __forceinline__ ushort f2bf(float x) {
    union { float f; unsigned u; } c; c.f = x;
    unsigned r = c.u + 0x7FFF + ((c.u >> 16) & 1);   // RNE
    return (ushort)(r >> 16);
}
__device__ __forceinline__ unsigned pk2(float hi, float lo) {
    union { float f; unsigned u; } a, b; a.f = hi; b.f = lo;
    return __builtin_amdgcn_perm(a.u, b.u, 0x07060302u);
}
__device__ __forceinline__ uint4 cvt8f(const float* p) {
    float4 a = *(const float4*)p;
    float4 b = *(const float4*)(p + 4);
    uint4 r;
    r.x = pk2(a.y, a.x); r.y = pk2(a.w, a.z);
    r.z = pk2(b.y, b.x); r.w = pk2(b.w, b.z);
    return r;
}
#define EXP2(x) __builtin_amdgcn_exp2f(x)

// ---- kv projection, 4x-parallel slice decomposition (R9-verified numerics):
// 256 blocks x 1024 thr; block -> 16 scene rows x 256 cols (k half or vT
// half). Wave w owns cols [cB + w*16, cB + w*16 + 16); acc = 4 rows/lane.
// Same K-accumulation order as the 64-block gemm -> bit-identical output.
__global__ __launch_bounds__(1024, 2) void kv_kernel(
    const float* __restrict__ scene,
    const float* __restrict__ in_w, const float* __restrict__ in_b,
    ushort* __restrict__ kb, ushort* __restrict__ vtb)
{
    __shared__ ushort kvA[16 * 64];           // A slice [16 rows][64 k]
    __shared__ ushort kvB[256 * 64];          // W slice [256 cols][64 k]

    const int t = threadIdx.x;
    const int w = t >> 6, lane = t & 63, g = lane >> 4, l15 = lane & 15;
    const int kvt = blockIdx.x >> 2;              // 0..63 tile
    const int cB  = (kvt >> 5) * 256;             // col base: 0=k, 256=v
    const int r0  = (kvt & 31) * 64 + (blockIdx.x & 3) * 16;  // scene row
    const float* Wkv = in_w + 65536;
    const float* bkv = in_b + 256;
    f32x4 acc = (f32x4){0.f,0.f,0.f,0.f};

    uint4 av;
    if (t < 128) av = cvt8f(scene + (size_t)(r0 + (t >> 3)) * 256 + (t & 7)*8);
    uint4 bv[2];
    #pragma unroll
    for (int i = 0; i < 2; i++) {
        const int u = t + 1024*i, br = u >> 3, gi = u & 7;
        bv[i] = cvt8f(Wkv + (size_t)(cB + br) * 256 + gi*8);
    }
    for (int k0 = 0; k0 < 256; k0 += 64) {
        __syncthreads();
        if (t < 128) {
            const int row = t >> 3, gi = t & 7;
            *(uint4*)&kvA[row*64 + (gi ^ (row & 7))*8] = av;
        }
        #pragma unroll
        for (int i = 0; i < 2; i++) {
            const int u = t + 1024*i, br = u >> 3, gi = u & 7;
            *(uint4*)&kvB[br*64 + (gi ^ (br & 7))*8] = bv[i];
        }
        __syncthreads();
        if (k0 < 192) {
            if (t < 128)
                av = cvt8f(scene + (size_t)(r0 + (t >> 3)) * 256 + k0 + 64 + (t & 7)*8);
            #pragma unroll
            for (int i = 0; i < 2; i++) {
                const int u = t + 1024*i, br = u >> 3, gi = u & 7;
                bv[i] = cvt8f(Wkv + (size_t)(cB + br) * 256 + k0 + 64 + gi*8);
            }
        }
        #pragma unroll
        for (int kk = 0; kk < 2; kk++) {
            const int swz = ((kk*4 + g) ^ (l15 & 7)) * 8;
            bf16x8 af = *(const bf16x8*)&kvA[l15*64 + swz];
            bf16x8 bf = *(const bf16x8*)&kvB[(w*16 + l15)*64 + swz];
            acc = __builtin_amdgcn_mfma_f32_16x16x32_bf16(af, bf, acc, 0, 0, 0);
        }
    }
    const int col = cB + w*16 + l15;
    const float bb = bkv[col];
    if (col < 256) {
        #pragma unroll
        for (int r = 0; r < 4; r++)
            kb[(size_t)(r0 + g*4 + r) * 256 + col] = f2bf(acc[r] + bb);
    } else {
        const int row0 = r0 + g*4;
        ushort4 pkv = { f2bf(acc[0] + bb), f2bf(acc[1] + bb),
                        f2bf(acc[2] + bb), f2bf(acc[3] + bb) };
        *(ushort4*)&vtb[(size_t)((row0 >> 9)*256 + col - 256) * 512 + (row0 & 511)] = pkv;
    }
}

// ---- MEGA: q-projection + attention (64 q rows) + full FFN tail per block.
// 256 blocks x 1024 thr = 16 waves, 1 block/CU, LDS 145.9KB (phase-aliased).
// Phase 0: q = bf16((hidden@Wq^T + bq)*alpha_q) -> Qb in LDS (never leaves CU).
// Pass 1 = R1 attn structure (LDS-staged K/V, register prefetch);
//          16 waves = 8 heads x 2 q-halves, Q read from Qb.
// ctx stays in LDS (Cb) -> ffn phase A reads it directly.
// Pass 2 reads Q from Qb; ffn = 16-wave structure, x residual in VGPRs.
// BEST MEASURED CONFIG (R6: total 167.2us) — unchanged.
__global__ __launch_bounds__(1024, 4) void mega_kernel(
    const float* __restrict__ hidden,
    const float* __restrict__ Wq, const float* __restrict__ bq,
    const ushort* __restrict__ k, const ushort* __restrict__ vt,
    const float* __restrict__ Wo, const float* __restrict__ bo,
    const float* __restrict__ ag, const float* __restrict__ ab,
    const float* __restrict__ W1, const float* __restrict__ b1,
    const float* __restrict__ W2, const float* __restrict__ b2,
    const float* __restrict__ fg, const float* __restrict__ fbv,
    float* __restrict__ out, float* __restrict__ attn_score,
    float alpha_q)
{
    __shared__ uint4 SHraw[9120];             // 145920 B
    ushort* SH = (ushort*)SHraw;
    // scratch arena [0, 78336) bytes — phase-aliased:
    ushort* Ks  = SH;                         // pass1 [32 key][264]      0..16896
    ushort* Vs  = SH + 8448;                  // pass1 [256 d][40]    16896..37376
    ushort* Pb  = SH + 18688;                 // pass1 16w x [32][40] 37376..78336
    ushort* As0 = SH;                         // phase0 A [64][64]        0..8192
    ushort* Bs0 = SH + 4096;                  // phase0 B [256][64]    8192..40960
    ushort* Bs  = SH;                         // ffn B [256][64]          0..32768
    float*  Ls  = (float*)(SH + 16384);       // [64][4]              32768..33792
    float*  Lq  = (float*)(SH + 16896);       // [64][4]              33792..34816
    // persistent / phase-paired:
    ushort* Qb  = SH + 39168;                 // q [64][256] swz      78336..111104
    ushort* Xb  = SH + 39168;                 // ffn x (aliases dead Qb)
    ushort* Cb  = SH + 55552;                 // ctx [64][256] swz   111104..143872
    ushort* Fb  = SH + 55552;                 // ffn f (aliases dead Cb) [64][128]
    float*  Lg  = (float*)(SH + 71936);       // [8 h][64 q]         143872..145920

    const int t = threadIdx.x;
    const int w = t >> 6, lane = t & 63, g = lane >> 4, l15 = lane & 15;
    const int b = blockIdx.x >> 6;
    const int m0 = (blockIdx.x & 63) * 64;
    const size_t rowG = (size_t)b * MQ + m0;      // 64 query rows
    const size_t kg = (size_t)b * NSC * H;
    const size_t vg = (size_t)b * H * NSC;

    const int wr = (w >> 2) * 16;     // 16-wave tiling: 4 row-grp x 16
    const int wc = (w & 3) * 64;      //                 4 col-grp x 64

    // ======= phase 0: q = bf16((hidden@Wq^T + bq)*alpha_q) =================
    {
        f32x4 acc[4];
        #pragma unroll
        for (int nt = 0; nt < 4; nt++) acc[nt] = (f32x4){0.f,0.f,0.f,0.f};

        const int sr = t >> 3, skc = t & 7, sp = skc ^ (sr & 7);
        uint4 av;
        if (t < 512) av = cvt8f(hidden + (rowG + sr) * 256 + skc*8);
        uint4 bv[2];
        #pragma unroll
        for (int i = 0; i < 2; i++) {
            const int u = t + 1024*i, br = u >> 3, bkc = u & 7;
            bv[i] = cvt8f(Wq + (size_t)br * 256 + bkc*8);
        }
        for (int k0 = 0; k0 < 256; k0 += 64) {
            __syncthreads();
            if (t < 512) *(uint4*)&As0[sr*64 + sp*8] = av;
            #pragma unroll
            for (int i = 0; i < 2; i++) {
                const int u = t + 1024*i, br = u >> 3, bkc = u & 7, bp = bkc ^ (br & 7);
                *(uint4*)&Bs0[br*64 + bp*8] = bv[i];
            }
            __syncthreads();
            if (k0 < 192) {
                if (t < 512) av = cvt8f(hidden + (rowG + sr) * 256 + k0 + 64 + skc*8);
                #pragma unroll
                for (int i = 0; i < 2; i++) {
                    const int u = t + 1024*i, br = u >> 3, bkc = u & 7;
                    bv[i] = cvt8f(Wq + (size_t)br * 256 + k0 + 64 + bkc*8);
                }
            }
            #pragma unroll
            for (int kk = 0; kk < 2; kk++) {
                const int swz = ((kk*4 + g) ^ (l15 & 7)) * 8;
                bf16x8 af = *(const bf16x8*)&As0[(wr + l15)*64 + swz];
                #pragma unroll
                for (int nt = 0; nt < 4; nt++) {
                    bf16x8 bfr = *(const bf16x8*)&Bs0[(wc + nt*16 + l15)*64 + swz];
                    acc[nt] = __builtin_amdgcn_mfma_f32_16x16x32_bf16(
                        af, bfr, acc[nt], 0, 0, 0);
                }
            }
        }
        #pragma unroll
        for (int nt = 0; nt < 4; nt++) {
            const int col = wc + nt*16 + l15;
            const float bb = bq[col];
            #pragma unroll
            for (int r = 0; r < 4; r++) {
                const int qr = wr + g*4 + r;
                const float o = (acc[nt][r] + bb) * alpha_q;
                Qb[qr*256 + (((col >> 3) ^ (qr & 7)) << 3) + (col & 7)] = f2bf(o);
            }
        }
    }
    __syncthreads();   // Qb complete; phase-0 scratch dead

    // ======= attn pass 1: denominators + ctx (wave = head hh0, half hf) ====
    const int hh0 = w & 7, hf = w >> 3;
    bf16x8 qf[2];
    #pragma unroll
    for (int qt = 0; qt < 2; qt++) {
        const int qr0 = hf*32 + qt*16 + l15;
        const int c0 = hh0*32 + g*8;
        qf[qt] = *(const bf16x8*)&Qb[qr0*256 + (((c0 >> 3) ^ (qr0 & 7)) << 3)];
    }

    f32x4 cacc[2][2];
    float lacc[2][4];
    #pragma unroll
    for (int qt = 0; qt < 2; qt++) {
        #pragma unroll
        for (int dt = 0; dt < 2; dt++) cacc[qt][dt] = (f32x4){0.f,0.f,0.f,0.f};
        #pragma unroll
        for (int r = 0; r < 4; r++) lacc[qt][r] = 0.f;
    }

    // staging assignment: 1024 thr cover 32 keys x 256 d (16KB K + 16KB V)
    const int skey = t >> 5, spart = t & 31;      // K: [key][d granule]
    const int sd = t >> 2, sp2 = t & 3;           // V: [d][key granule]
    bf16x8 kr = *(const bf16x8*)&k[kg + (size_t)skey*H + spart*8];
    bf16x8 vr = *(const bf16x8*)&vt[vg + (size_t)sd*NSC + sp2*8];

    for (int c = 0; c < 16; c++) {
        const int kbase = c * 32;
        __syncthreads();
        *(bf16x8*)&Ks[skey*264 + spart*8] = kr;
        *(bf16x8*)&Vs[sd*40 + sp2*8] = vr;
        __syncthreads();
        if (c < 15) {      // prefetch next chunk; latency hides under compute
            kr = *(const bf16x8*)&k[kg + (size_t)(kbase + 32 + skey)*H + spart*8];
            vr = *(const bf16x8*)&vt[vg + (size_t)sd*NSC + kbase + 32 + sp2*8];
        }
        #pragma unroll
        for (int qt = 0; qt < 2; qt++) {
            #pragma unroll
            for (int kt = 0; kt < 2; kt++) {
                bf16x8 kf = *(const bf16x8*)&Ks[(kt*16 + l15)*264 + hh0*32 + g*8];
                f32x4 s = __builtin_amdgcn_mfma_f32_16x16x32_bf16(
                    qf[qt], kf, (f32x4){0.f,0.f,0.f,0.f}, 0, 0, 0);
                #pragma unroll
                for (int r = 0; r < 4; r++) {
                    float p = EXP2(s[r]);
                    lacc[qt][r] += p;
                    Pb[(w*32 + qt*16 + g*4 + r)*40 + kt*16 + l15] = f2bf(p);
                }
            }
        }
        #pragma unroll
        for (int qt = 0; qt < 2; qt++) {
            bf16x8 pf = *(const bf16x8*)&Pb[(w*32 + qt*16 + l15)*40 + g*8];
            #pragma unroll
            for (int dt = 0; dt < 2; dt++) {
                bf16x8 vf = *(const bf16x8*)&Vs[(hh0*32 + dt*16 + l15)*40 + g*8];
                cacc[qt][dt] = __builtin_amdgcn_mfma_f32_16x16x32_bf16(
                    pf, vf, cacc[qt][dt], 0, 0, 0);
            }
        }
    }

    // pass-1 epilogue: l-reduce, Lg, ctx -> Cb (swizzled bf16, stays in LDS)
    #pragma unroll
    for (int qt = 0; qt < 2; qt++) {
        float invl[4];
        #pragma unroll
        for (int r = 0; r < 4; r++) {
            float v = lacc[qt][r];
            v += __shfl_xor(v, 1); v += __shfl_xor(v, 2);
            v += __shfl_xor(v, 4); v += __shfl_xor(v, 8);
            invl[r] = 1.f / v;
            if (l15 == 0) Lg[hh0*64 + hf*32 + qt*16 + g*4 + r] = -__log2f(v) - 3.0f;
        }
        #pragma unroll
        for (int dt = 0; dt < 2; dt++)
            #pragma unroll
            for (int r = 0; r < 4; r++) {
                const int qr = hf*32 + qt*16 + g*4 + r;
                const int col = hh0*32 + dt*16 + l15;
                Cb[qr*256 + (((col >> 3) ^ (qr & 7)) << 3) + (col & 7)]
                    = f2bf(cacc[qt][dt][r] * invl[r]);
            }
    }

    __syncthreads();   // pass-1 scratch dead; Cb/Lg complete

    // ======= attn pass 2: attn_score; wave w -> keys [32w, 32w+32) =========
    {
        f32x4 sacc[4][2];
        #pragma unroll
        for (int qt = 0; qt < 4; qt++)
            #pragma unroll
            for (int kt = 0; kt < 2; kt++) sacc[qt][kt] = (f32x4){0.f,0.f,0.f,0.f};

        #pragma unroll 2
        for (int h = 0; h < 8; h++) {
            float lgq[4]; bf16x8 qv[4];
            #pragma unroll
            for (int qt = 0; qt < 4; qt++) {
                lgq[qt] = Lg[h*64 + qt*16 + l15];
                const int qr0 = qt*16 + l15;
                const int c0 = h*32 + g*8;
                qv[qt] = *(const bf16x8*)&Qb[qr0*256 + (((c0 >> 3) ^ (qr0 & 7)) << 3)];
            }
            #pragma unroll
            for (int kt = 0; kt < 2; kt++) {
                bf16x8 kf2 = *(const bf16x8*)&k[kg + (size_t)(w*32 + kt*16 + l15)*H + h*32 + g*8];
                #pragma unroll
                for (int qt = 0; qt < 4; qt++) {
                    f32x4 s = __builtin_amdgcn_mfma_f32_16x16x32_bf16(
                        kf2, qv[qt], (f32x4){0.f,0.f,0.f,0.f}, 0, 0, 0);
                    #pragma unroll
                    for (int r = 0; r < 4; r++) sacc[qt][kt][r] += EXP2(s[r] + lgq[qt]);
                }
            }
        }
        #pragma unroll
        for (int qt = 0; qt < 4; qt++)
            #pragma unroll
            for (int kt = 0; kt < 2; kt++)
                *(f32x4*)&attn_score[(rowG + qt*16 + l15)*NSC + w*32 + kt*16 + g*4]
                    = sacc[qt][kt];
    }

    // ======= ffn phase A: x = LN(ctx @ Wo^T + bo + hid) ====================
    float xres[4][4];
    {
        f32x4 acc[4];
        #pragma unroll
        for (int nt = 0; nt < 4; nt++) acc[nt] = (f32x4){0.f,0.f,0.f,0.f};

        uint4 bv[2];
        #pragma unroll
        for (int i = 0; i < 2; i++) {
            const int u = t + 1024*i, br = u >> 3, bkc = u & 7;
            bv[i] = cvt8f(Wo + (size_t)br * 256 + bkc*8);
        }
        for (int k0 = 0; k0 < 256; k0 += 64) {
            __syncthreads();
            #pragma unroll
            for (int i = 0; i < 2; i++) {
                const int u = t + 1024*i, br = u >> 3, bkc = u & 7, bp = bkc ^ (br & 7);
                *(uint4*)&Bs[br*64 + bp*8] = bv[i];
            }
            __syncthreads();
            if (k0 < 192) {
                #pragma unroll
                for (int i = 0; i < 2; i++) {
                    const int u = t + 1024*i, br = u >> 3, bkc = u & 7;
                    bv[i] = cvt8f(Wo + (size_t)br * 256 + k0 + 64 + bkc*8);
                }
            }
            #pragma unroll
            for (int kk = 0; kk < 2; kk++) {
                const int rowC = wr + l15;
                const int gi = (k0 >> 3) + kk*4 + g;
                bf16x8 af = *(const bf16x8*)&Cb[rowC*256 + ((gi ^ (rowC & 7)) << 3)];
                const int swz = ((kk*4 + g) ^ (l15 & 7)) * 8;
                #pragma unroll
                for (int nt = 0; nt < 4; nt++) {
                    bf16x8 bfr = *(const bf16x8*)&Bs[(wc + nt*16 + l15)*64 + swz];
                    acc[nt] = __builtin_amdgcn_mfma_f32_16x16x32_bf16(
                        af, bfr, acc[nt], 0, 0, 0);
                }
            }
        }
        // epilogue A: + bias + residual, LN, f32 -> xres, bf16 -> Xb
        float bb[4], gmv[4], btv[4];
        #pragma unroll
        for (int nt = 0; nt < 4; nt++) {
            const int col = wc + nt*16 + l15;
            bb[nt] = bo[col]; gmv[nt] = ag[col]; btv[nt] = ab[col];
        }
        #pragma unroll
        for (int r = 0; r < 4; r++) {
            const float* rp = hidden + (rowG + wr + g*4 + r) * 256;
            #pragma unroll
            for (int nt = 0; nt < 4; nt++)
                acc[nt][r] += bb[nt] + rp[wc + nt*16 + l15];
        }
        float ps[4], pq[4];
        #pragma unroll
        for (int r = 0; r < 4; r++) {
            float s = (acc[0][r] + acc[1][r]) + (acc[2][r] + acc[3][r]);
            float qq = (acc[0][r]*acc[0][r] + acc[1][r]*acc[1][r])
                     + (acc[2][r]*acc[2][r] + acc[3][r]*acc[3][r]);
            #pragma unroll
            for (int m = 1; m < 16; m <<= 1) {
                s += __shfl_xor(s, m);
                qq += __shfl_xor(qq, m);
            }
            ps[r] = s; pq[r] = qq;
        }
        if (l15 == 0) {
            #pragma unroll
            for (int r = 0; r < 4; r++) {
                const int ri = wr + g*4 + r;
                Ls[ri*4 + (w & 3)] = ps[r];
                Lq[ri*4 + (w & 3)] = pq[r];
            }
        }
        __syncthreads();
        #pragma unroll
        for (int r = 0; r < 4; r++) {
            const int ri = wr + g*4 + r;
            f32x4 sv = *(const f32x4*)&Ls[ri*4];
            f32x4 qv2 = *(const f32x4*)&Lq[ri*4];
            const float mu = (sv[0]+sv[1]+sv[2]+sv[3]) * (1.f/256.f);
            const float ex2 = (qv2[0]+qv2[1]+qv2[2]+qv2[3]) * (1.f/256.f);
            const float rs = rsqrtf(ex2 - mu*mu + 1e-6f);
            #pragma unroll
            for (int nt = 0; nt < 4; nt++) {
                const int col = wc + nt*16 + l15;
                const float o = (acc[nt][r] - mu) * rs * gmv[nt] + btv[nt];
                xres[nt][r] = o;
                Xb[ri*256 + (((col >> 3) ^ (ri & 7)) << 3) + (col & 7)] = f2bf(o);
            }
        }
    }

    // ======= ffn phase B: f = relu(x @ W1^T + b1) ==========================
    {
        const int wrB = (w >> 2) * 16;
        const int wcB = (w & 3) * 32;
        f32x4 facc[2];
        #pragma unroll
        for (int nt = 0; nt < 2; nt++) facc[nt] = (f32x4){0.f,0.f,0.f,0.f};

        uint4 bv2 = cvt8f(W1 + (size_t)(t >> 3) * 256 + (t & 7)*8);
        for (int k0 = 0; k0 < 256; k0 += 64) {
            __syncthreads();
            {
                const int br = t >> 3, bkc = t & 7, bp = bkc ^ (br & 7);
                *(uint4*)&Bs[br*64 + bp*8] = bv2;
            }
            __syncthreads();
            if (k0 < 192)
                bv2 = cvt8f(W1 + (size_t)(t >> 3) * 256 + k0 + 64 + (t & 7)*8);
            #pragma unroll
            for (int kk = 0; kk < 2; kk++) {
                const int rowX = wrB + l15;
                const int gi = (k0 >> 3) + kk*4 + g;
                bf16x8 af = *(const bf16x8*)&Xb[rowX*256 + ((gi ^ (rowX & 7)) << 3)];
                const int swz = ((kk*4 + g) ^ (l15 & 7)) * 8;
                #pragma unroll
                for (int nt = 0; nt < 2; nt++) {
                    bf16x8 bfr = *(const bf16x8*)&Bs[(wcB + nt*16 + l15)*64 + swz];
                    facc[nt] = __builtin_amdgcn_mfma_f32_16x16x32_bf16(
                        af, bfr, facc[nt], 0, 0, 0);
                }
            }
        }
        __syncthreads();   // Fb aliases dead Cb: phase-A Cb reads done
        #pragma unroll
        for (int nt = 0; nt < 2; nt++) {
            const int colF = wcB + nt*16 + l15;
            const float fbb = b1[colF];
            #pragma unroll
            for (int r = 0; r < 4; r++) {
                const int rowF = wrB + g*4 + r;
                const float o = fmaxf(facc[nt][r] + fbb, 0.f);
                Fb[rowF*128 + (((colF >> 3) ^ (rowF & 7)) << 3) + (colF & 7)] = f2bf(o);
            }
        }
        __syncthreads();
    }

    // ======= ffn phase C: out = LN(f @ W2^T + b2 + x) ======================
    {
        f32x4 acc2[4];
        #pragma unroll
        for (int nt = 0; nt < 4; nt++) acc2[nt] = (f32x4){0.f,0.f,0.f,0.f};

        uint4 bv3[2];
        #pragma unroll
        for (int i = 0; i < 2; i++) {
            const int u = t + 1024*i, br = u >> 3, bkc = u & 7;
            bv3[i] = cvt8f(W2 + (size_t)br * 128 + bkc*8);
        }
        for (int k0 = 0; k0 < 128; k0 += 64) {
            __syncthreads();
            #pragma unroll
            for (int i = 0; i < 2; i++) {
                const int u = t + 1024*i, br = u >> 3, bkc = u & 7, bp = bkc ^ (br & 7);
                *(uint4*)&Bs[br*64 + bp*8] = bv3[i];
            }
            __syncthreads();
            if (k0 == 0) {
                #pragma unroll
                for (int i = 0; i < 2; i++) {
                    const int u = t + 1024*i, br = u >> 3, bkc = u & 7;
                    bv3[i] = cvt8f(W2 + (size_t)br * 128 + 64 + bkc*8);
                }
            }
            #pragma unroll
            for (int kk = 0; kk < 2; kk++) {
                const int gi = (k0 >> 3) + kk*4 + g;
                const int rowF = wr + l15;
                bf16x8 af2 = *(const bf16x8*)&Fb[rowF*128 + ((gi ^ (rowF & 7)) << 3)];
                const int swz = ((kk*4 + g) ^ (l15 & 7)) * 8;
                #pragma unroll
                for (int nt = 0; nt < 4; nt++) {
                    bf16x8 bfr = *(const bf16x8*)&Bs[(wc + nt*16 + l15)*64 + swz];
                    acc2[nt] = __builtin_amdgcn_mfma_f32_16x16x32_bf16(
                        af2, bfr, acc2[nt], 0, 0, 0);
                }
            }
        }
        float bb[4], gmv[4], btv[4];
        #pragma unroll
        for (int nt = 0; nt < 4; nt++) {
            const int col = wc + nt*16 + l15;
            bb[nt] = b2[col]; gmv[nt] = fg[col]; btv[nt] = fbv[col];
        }
        #pragma unroll
        for (int r = 0; r < 4; r++)
            #pragma unroll
            for (int nt = 0; nt < 4; nt++)
                acc2[nt][r] += bb[nt] + xres[nt][r];
        float ps[4], pq[4];
        #pragma unroll
        for (int r = 0; r < 4; r++) {
            float s = (acc2[0][r] + acc2[1][r]) + (acc2[2][r] + acc2[3][r]);
            float qq = (acc2[0][r]*acc2[0][r] + acc2[1][r]*acc2[1][r])
                     + (acc2[2][r]*acc2[2][r] + acc2[3][r]*acc2[3][r]);
            #pragma unroll
            for (int m = 1; m < 16; m <<= 1) {
                s += __shfl_xor(s, m);
                qq += __shfl_xor(qq, m);
            }
            ps[r] = s; pq[r] = qq;
        }
        __syncthreads();   // Ls/Lq reuse guard
        if (l15 == 0) {
            #pragma unroll
            for (int r = 0; r < 4; r++) {
                const int ri = wr + g*4 + r;
                Ls[ri*4 + (w & 3)] = ps[r];
                Lq[ri*4 + (w & 3)] = pq[r];
            }
        }
        __syncthreads();
        #pragma unroll
        for (int r = 0; r < 4; r++) {
            const int ri = wr + g*4 + r;
            f32x4 sv = *(const f32x4*)&Ls[ri*4];
            f32x4 qv2 = *(const f32x4*)&Lq[ri*4];
            const float mu = (sv[0]+sv[1]+sv[2]+sv[3]) * (1.f/256.f);
            const float ex2 = (qv2[0]+qv2[1]+qv2[2]+qv2[3]) * (1.f/256.f);
            const float rs = rsqrtf(ex2 - mu*mu + 1e-6f);
            #pragma unroll
            for (int nt = 0; nt < 4; nt++) {
                const int col = wc + nt*16 + l15;
                out[(rowG + ri) * 256 + col] =
                    (acc2[nt][r] - mu) * rs * gmv[nt] + btv[nt];
            }
        }
    }
}

extern "C" void kernel_launch(void* const* d_in, const int* in_sizes, int n_in,
                              void* d_out, int out_size, void* d_ws, size_t ws_size,
                              hipStream_t stream)
{
    const float* hidden = (const float*)d_in[0];
    const float* scene  = (const float*)d_in[1];
    const float* in_w   = (const float*)d_in[2];
    const float* in_b   = (const float*)d_in[3];
    const float* out_w  = (const float*)d_in[4];
    const float* out_b  = (const float*)d_in[5];
    const float* aln_g  = (const float*)d_in[6];
    const float* aln_b  = (const float*)d_in[7];
    const float* ff1_w  = (const float*)d_in[8];
    const float* ff1_b  = (const float*)d_in[9];
    const float* ff2_w  = (const float*)d_in[10];
    const float* ff2_b  = (const float*)d_in[11];
    const float* fln_g  = (const float*)d_in[12];
    const float* fln_b  = (const float*)d_in[13];

    float* out0  = (float*)d_out;
    float* score = out0 + (size_t)BATCH * MQ * H;

    ushort* kb   = (ushort*)d_ws;                    // 2048x256 bf16
    ushort* vtb  = kb + 524288;                      // [b][256][512] bf16

    // (1/sqrt(32)) * log2(e): q pre-scaled so attn uses exp2 directly
    const float alpha_q = 0.25507609683638066f;

    // k/vT projection, 4x-parallel slice decomposition (256 blocks)
    kv_kernel<<<dim3(256), dim3(1024), 0, stream>>>(scene, in_w, in_b, kb, vtb);
    // fused q-proj + attention + FFN: q and ctx never leave LDS
    mega_kernel<<<dim3(256), dim3(1024), 0, stream>>>(
        hidden, in_w, in_b, kb, vtb,
        out_w, out_b, aln_g, aln_b,
        ff1_w, ff1_b, ff2_w, ff2_b, fln_g, fln_b,
        out0, score, alpha_q);
}